// Round 5
// baseline (169.881 us; speedup 1.0000x reference)
//
#include <hip/hip_runtime.h>

// NodeClassifier 3-layer MP-GNN, MI355X. R10b: resubmit of R10 (container
// acquisition failed twice = infra, same as R1; code audited: ws 31.65MB of
// 256MiB, LDS 156.5KB < 160KB, no unbounded loops, no divergent barriers).
// R9 post-mortem: all kernels <44us but total stuck at 160. Budget:
// prep/place/agg40/gaps ~45us; gather+gemm ~115us. Gather moves 164MB/layer
// from a 5MB array at ~4.7 TB/s = L3-bound: random src order thrashes the
// 4MiB per-XCD L2. Gemm: 625 blocks x 16 k-steps x 2 barriers, W re-staged
// 16x/block = ~20us for 1.3 GFLOP.
// Fixes: (1) edges bucketed by (dst, src>>10): 10 sub-bins of 1024 src nodes
// = 512KB L2-resident window; resident waves sweep bins in phase -> gather
// from L2 not L3. Cursor lines 10x more -> atomic contention 512->51/line.
// (2) gemm: whole W in LDS once (256x264 bf16 = 132KB), 64-row blocks,
// 8 waves, 157 blocks = 1 round, A-frags preloaded from global, ZERO k-loop
// barriers, 64 MFMA back-to-back. Chain keeps W3 in spare LDS.
// Lessons: grid.sync ~35us (R3); fused gather+gemm = idle pipes (R2);
// source-level load pipelining defeated by compiler (R8).

#define N_NODES   10000
#define N_EDGES   320000
#define D_HID     256
#define N_CLASSES 40
#define NSB       10     // src sub-blocks: sb = src >> 10 (1024 nodes = 512KB)
#define CAP_S     24     // per-(dst,sb) capacity; Poisson(3.28) overflow ~1e-9 total
#define DUMMY     10000  // padding node; its rows are zeroed

typedef __attribute__((ext_vector_type(8))) short short8;
typedef __attribute__((ext_vector_type(4))) float f32x4;

__device__ __forceinline__ ushort f2bf(float f) {
    unsigned u = __float_as_uint(f);
    u = (u + 0x7fffu + ((u >> 16) & 1u)) >> 16;   // RNE; inputs finite
    return (ushort)u;
}
__device__ __forceinline__ float bf2f(ushort u) {
    return __uint_as_float(((unsigned)u) << 16);
}

// ---------------- prep: zero cur2, dummy-fill esrc2, pad rows, bf16 conv ----------------

__global__ __launch_bounds__(256)
void prep_kernel(const float* __restrict__ X,
                 const float* __restrict__ W1, const float* __restrict__ W2,
                 const float* __restrict__ W3,
                 ushort* __restrict__ Xb, ushort* __restrict__ bufY,
                 ushort* __restrict__ bufH,
                 ushort* __restrict__ W1b, ushort* __restrict__ W2b,
                 ushort* __restrict__ W3b, int* __restrict__ cur2,
                 int* __restrict__ esrc2) {
    const int tid  = blockIdx.x * 256 + threadIdx.x;
    const int nthr = gridDim.x * 256;
    for (int i = tid; i < N_NODES * NSB; i += nthr) cur2[i] = 0;
    // dummy-fill all sub-bin slots (padding node DUMMY has a zero row)
    for (int i = tid; i < N_NODES * NSB * CAP_S; i += nthr) esrc2[i] = DUMMY;
    // zero the padding rows
    ushort4 z; z.x = 0; z.y = 0; z.z = 0; z.w = 0;
    if (tid < 64) {
        ((ushort4*)Xb)[640000 + tid]   = z;   // row 10000 of Xb
        ((ushort4*)bufY)[640000 + tid] = z;   // row 10000 of bufY
    }
    if (tid < 10) ((ushort4*)bufH)[100000 + tid] = z;  // row 10000 of bufH
    // X -> bf16
    for (int i = tid; i < N_NODES * D_HID / 4; i += nthr) {
        float4 v = ((const float4*)X)[i];
        ushort4 o;
        o.x = f2bf(v.x); o.y = f2bf(v.y); o.z = f2bf(v.z); o.w = f2bf(v.w);
        ((ushort4*)Xb)[i] = o;
    }
    // weights -> bf16, transposed to n-major
    for (int i = tid; i < 141312; i += nthr) {
        if (i < 65536) {
            int n = i >> 8, k = i & 255;
            W1b[i] = f2bf(W1[k * 256 + n]);
        } else if (i < 131072) {
            int t2 = i - 65536;
            int n = t2 >> 8, k = t2 & 255;
            W2b[t2] = f2bf(W2[k * 256 + n]);
        } else {
            int t2 = i - 131072;
            int n = t2 >> 8, k = t2 & 255;
            W3b[t2] = f2bf(W3[k * N_CLASSES + n]);
        }
    }
}

// ---------------- place: (dst, src>>10) sub-bin CSR via global atomics ----------------

__global__ __launch_bounds__(256)
void place_kernel(const int* __restrict__ edges, int* __restrict__ cur2,
                  int* __restrict__ esrc2) {
    int e = blockIdx.x * 256 + threadIdx.x;
    if (e < N_EDGES) {
        int s = edges[e];
        int d = edges[N_EDGES + e];
        int sb = s >> 10;                           // 0..9
        int bin = d * NSB + sb;
        int pos = atomicAdd(&cur2[bin], 1);
        if (pos < CAP_S) esrc2[bin * CAP_S + pos] = s;
    }
}

// ---------------- gather: Ag[n] = sum_edges Xin[src]; degOut[n] = true degree ----------------
// 1 wave = 1 node, 4/block, 2500 blocks (32 waves/CU). Sub-bin loop 0..9 keeps
// all resident waves inside the same 512KB src window (L2-resident). Batch =
// 4 edges = 2 uint4 loads (lanes 0-31 edge b, 32-63 edge b+1); dummy-padded
// slots read the hot zero row. Halves combined via shfl_xor(32).

__global__ __launch_bounds__(256)
void gather_kernel(const ushort* __restrict__ Xin, const int* __restrict__ cur2,
                   const int* __restrict__ esrc2, ushort* __restrict__ Ag,
                   float* __restrict__ degOut) {
    __shared__ int eidx[4 * NSB * CAP_S];   // 960 ints, 3840 B
    __shared__ int cnts[4 * NSB];

    const int tid  = threadIdx.x;
    const int w    = tid >> 6, lane = tid & 63;
    const int lo   = lane & 31, hi = lane >> 5;
    const int base = blockIdx.x * 4;

    for (int i = tid; i < 4 * NSB * CAP_S; i += 256)
        eidx[i] = esrc2[base * NSB * CAP_S + i];
    if (tid < 4 * NSB) cnts[tid] = cur2[base * NSB + tid];
    __syncthreads();

    const int node = base + w;
    const uint4* hp4 = (const uint4*)Xin;
    float a[8] = {};
    int degT = 0;
    for (int sb = 0; sb < NSB; ++sb) {
        int raw = cnts[w * NSB + sb];
        degT += raw;
        int cnt = raw < CAP_S ? raw : CAP_S;
        const int* ep = eidx + (w * NSB + sb) * CAP_S;
        for (int b = 0; b < cnt; b += 4) {          // slots b..b+3 (dummy-padded)
            int e0 = ep[b + hi];
            int e1 = ep[b + 2 + hi];
            uint4 v0 = hp4[(size_t)e0 * 32 + lo];
            uint4 v1 = hp4[(size_t)e1 * 32 + lo];
            a[0] += bf2f((ushort)(v0.x & 0xffff)); a[1] += bf2f((ushort)(v0.x >> 16));
            a[2] += bf2f((ushort)(v0.y & 0xffff)); a[3] += bf2f((ushort)(v0.y >> 16));
            a[4] += bf2f((ushort)(v0.z & 0xffff)); a[5] += bf2f((ushort)(v0.z >> 16));
            a[6] += bf2f((ushort)(v0.w & 0xffff)); a[7] += bf2f((ushort)(v0.w >> 16));
            a[0] += bf2f((ushort)(v1.x & 0xffff)); a[1] += bf2f((ushort)(v1.x >> 16));
            a[2] += bf2f((ushort)(v1.y & 0xffff)); a[3] += bf2f((ushort)(v1.y >> 16));
            a[4] += bf2f((ushort)(v1.z & 0xffff)); a[5] += bf2f((ushort)(v1.z >> 16));
            a[6] += bf2f((ushort)(v1.w & 0xffff)); a[7] += bf2f((ushort)(v1.w >> 16));
        }
    }
#pragma unroll
    for (int j = 0; j < 8; ++j) a[j] += __shfl_xor(a[j], 32);
    if (lane < 32) {
        uint4 o;
        o.x = (unsigned)f2bf(a[0]) | ((unsigned)f2bf(a[1]) << 16);
        o.y = (unsigned)f2bf(a[2]) | ((unsigned)f2bf(a[3]) << 16);
        o.z = (unsigned)f2bf(a[4]) | ((unsigned)f2bf(a[5]) << 16);
        o.w = (unsigned)f2bf(a[6]) | ((unsigned)f2bf(a[7]) << 16);
        ((uint4*)(Ag + (size_t)node * 256))[lo] = o;   // zero-deg -> zero row
    }
    if (lane == 0) degOut[node] = (float)degT;
}

// ---------------- gemm: Out = relu(Ag @ W + deg*b)  [+ chained @W3 + b3] ----------------
// 64 rows x 256 cols per block, 512 threads (8 waves: 4 rowGrp x 2 colGrp),
// 157 blocks = single dispatch round. W staged to LDS ONCE (256x264 stride,
// 2-way-free banks), A-frags preloaded to regs from global (16 full 64B lines
// per load instr), k-loop = 64 MFMA back-to-back, ZERO barriers inside.
// Rows 10000..10047 are pad: A poison stays in its own C row; stores guarded.

#define LDSB 264

template<bool CHAIN>
__global__ __launch_bounds__(512)
void gemm_kernel(const ushort* __restrict__ Ag, const ushort* __restrict__ Bt,
                 const float* __restrict__ bias, const float* __restrict__ degF,
                 const ushort* __restrict__ W3b, const float* __restrict__ b3,
                 ushort* __restrict__ Out) {
    __shared__ ushort Bs[256 * LDSB];     // 135,168 B; W2-main, reused as out2 when CHAIN
    __shared__ ushort W3L[40 * LDSB];     // 21,120 B (staged only when CHAIN)
    __shared__ float  degL[64];

    const int tid  = threadIdx.x;
    const int wave = tid >> 6, lane = tid & 63;
    const int lr = lane & 15, lg = lane >> 4;
    const int rg = wave >> 1, cg = wave & 1;
    const int rowBase = blockIdx.x * 64;

    // stage W: 256 n-rows x 256 k -> Bs[n*LDSB + k]; 8192 16B chunks
#pragma unroll
    for (int p = 0; p < 16; ++p) {
        int idx = p * 512 + tid;
        int n = idx >> 5, c = (idx & 31) * 8;
        *(uint4*)(Bs + n * LDSB + c) = *(const uint4*)(Bt + (size_t)n * 256 + c);
    }
    if (CHAIN) {
#pragma unroll
        for (int p = 0; p < 3; ++p) {
            int idx = p * 512 + tid;
            if (idx < 1280) {
                int n = idx >> 5, c = (idx & 31) * 8;
                *(uint4*)(W3L + n * LDSB + c) = *(const uint4*)(W3b + (size_t)n * 256 + c);
            }
        }
    }
    if (tid < 64) degL[tid] = degF[rowBase + tid];

    // preload all 8 A-fragments (this wave's 16 rows, full K) from global
    short8 afr[8];
    const size_t aBase = (size_t)(rowBase + rg * 16 + lr) * 256 + lg * 8;
#pragma unroll
    for (int ks = 0; ks < 8; ++ks)
        afr[ks] = *(const short8*)(Ag + aBase + ks * 32);

    __syncthreads();

    f32x4 acc[8] = {};
#pragma unroll
    for (int ks = 0; ks < 8; ++ks) {
        int k0 = ks * 32;
#pragma unroll
        for (int j = 0; j < 8; ++j) {
            short8 bf = *(const short8*)(Bs + (cg * 128 + j * 16 + lr) * LDSB + k0 + lg * 8);
            acc[j] = __builtin_amdgcn_mfma_f32_16x16x32_bf16(afr[ks], bf, acc[j], 0, 0, 0);
        }
    }

    if (!CHAIN) {
#pragma unroll
        for (int j = 0; j < 8; ++j) {
            int col = cg * 128 + j * 16 + lr;
            float bv = bias[col];
#pragma unroll
            for (int r = 0; r < 4; ++r) {
                int rl = rg * 16 + lg * 4 + r;
                int grow = rowBase + rl;
                if (grow < N_NODES)
                    Out[(size_t)grow * 256 + col] =
                        f2bf(fmaxf(fmaf(degL[rl], bv, acc[j][r]), 0.f));
            }
        }
    } else {
        __syncthreads();   // all Bs reads done before overwrite
        // out2 = relu(acc + deg*b) -> Bs area as As3[64][LDSB] (bf16)
#pragma unroll
        for (int j = 0; j < 8; ++j) {
            int col = cg * 128 + j * 16 + lr;
            float bv = bias[col];
#pragma unroll
            for (int r = 0; r < 4; ++r) {
                int rl = rg * 16 + lg * 4 + r;
                Bs[rl * LDSB + col] = f2bf(fmaxf(fmaf(degL[rl], bv, acc[j][r]), 0.f));
            }
        }
        __syncthreads();
        // gemm3: h3 = out2 @ W3 + b3. 12 tiles (4 rowT x 3 colT, mask 40).
        for (int t = wave; t < 12; t += 8) {
            int rT = t & 3, cT = t >> 2;
            f32x4 a3 = {};
#pragma unroll
            for (int ks = 0; ks < 8; ++ks) {
                short8 af = *(const short8*)(Bs + (rT * 16 + lr) * LDSB + ks * 32 + lg * 8);
                short8 bf = *(const short8*)(W3L + (cT * 16 + lr) * LDSB + ks * 32 + lg * 8);
                a3 = __builtin_amdgcn_mfma_f32_16x16x32_bf16(af, bf, a3, 0, 0, 0);
            }
            int col = cT * 16 + lr;
            if (col < N_CLASSES) {
                float bv = b3[col];
#pragma unroll
                for (int r = 0; r < 4; ++r) {
                    int grow = rowBase + rT * 16 + lg * 4 + r;
                    if (grow < N_NODES)
                        Out[(size_t)grow * N_CLASSES + col] = f2bf(a3[r] + bv);
                }
            }
        }
    }
}

// ---------------- agg40: out = relu(segsum(h3[src])) -> f32 ----------------
// One wave per node; sub-bin loop; batch = 6 edges (10 lanes x 4 cols each,
// lanes 60-63 idle-duplicate), dummy-padded; 3-round shuffle fold at the end.

__global__ __launch_bounds__(256)
void agg_relu_40_kernel(const ushort* __restrict__ h, const int* __restrict__ cur2,
                        const int* __restrict__ esrc2, float* __restrict__ out) {
    const int wv   = threadIdx.x >> 6;
    const int lane = threadIdx.x & 63;
    const int node = (blockIdx.x << 2) + wv;
    const int l6   = (lane < 60) ? lane : 0;
    const int g6   = l6 / 10;                 // edge-in-batch 0..5
    const int c10  = l6 - g6 * 10;            // col group 0..9 (cols 4*c10..+3)

    const int* cp  = cur2 + node * NSB;
    const int* ep2 = esrc2 + node * NSB * CAP_S;
    float a0 = 0.f, a1 = 0.f, a2 = 0.f, a3 = 0.f;
    for (int sb = 0; sb < NSB; ++sb) {
        int cnt = cp[sb];
        if (cnt > CAP_S) cnt = CAP_S;
        const int* ep = ep2 + sb * CAP_S;
        for (int b = 0; b < cnt; b += 6) {        // slots b..b+5 (dummy-padded)
            int s = ep[b + g6];
            uint2 v = *(const uint2*)(h + (size_t)s * N_CLASSES + c10 * 4);
            a0 += bf2f((ushort)(v.x & 0xffff)); a1 += bf2f((ushort)(v.x >> 16));
            a2 += bf2f((ushort)(v.y & 0xffff)); a3 += bf2f((ushort)(v.y >> 16));
        }
    }
    // fold 6 edge-groups down to group 0 (lanes 0..9): +30, then +10 and +20
#define FOLD40(x) { x += __shfl(x, lane + 30);                      \
                    float t1 = __shfl(x, lane + 10);                \
                    float t2 = __shfl(x, lane + 20);                \
                    x += t1 + t2; }
    FOLD40(a0); FOLD40(a1); FOLD40(a2); FOLD40(a3);
#undef FOLD40
    if (lane < 10) {
        float4 o;
        o.x = fmaxf(a0, 0.f); o.y = fmaxf(a1, 0.f);
        o.z = fmaxf(a2, 0.f); o.w = fmaxf(a3, 0.f);
        *(float4*)(out + (size_t)node * N_CLASSES + lane * 4) = o;
    }
}

// ---------------- launch ----------------

extern "C" void kernel_launch(void* const* d_in, const int* in_sizes, int n_in,
                              void* d_out, int out_size, void* d_ws, size_t ws_size,
                              hipStream_t stream) {
    const float* X     = (const float*)d_in[0];
    const int*   edges = (const int*)d_in[1];
    const float* W1 = (const float*)d_in[2];
    const float* b1 = (const float*)d_in[3];
    const float* W2 = (const float*)d_in[4];
    const float* b2 = (const float*)d_in[5];
    const float* W3 = (const float*)d_in[6];
    const float* b3 = (const float*)d_in[7];
    float* out = (float*)d_out;

    char* ws = (char*)d_ws;
    ushort* Xb    = (ushort*)(ws);                   //  5,120,512 B (10001 x 256)
    ushort* bufY  = (ushort*)(ws + 5120512);         //  5,120,512 B (10001 x 256)
    ushort* bufH  = (ushort*)(ws + 10241024);        //    800,080 B (10001 x 40)
    ushort* W1b   = (ushort*)(ws + 11041104);        //    131,072 B (n-major)
    ushort* W2b   = (ushort*)(ws + 11172176);        //    131,072 B
    ushort* W3b   = (ushort*)(ws + 11303248);        //     20,480 B
    int*    cur2  = (int*)(ws + 11323728);           //    400,000 B (10000 x 10)
    int*    esrc2 = (int*)(ws + 11723728);           //  9,600,000 B (10000 x 10 x 24)
    ushort* Ag1   = (ushort*)(ws + 21323728);        //  5,144,576 B (10048 x 256)
    ushort* Ag2   = (ushort*)(ws + 26468304);        //  5,144,576 B
    float*  degF  = (float*)(ws + 31612880);         //     40,192 B (10048)

    // 1: conversions + zero cur2 + dummy-fill esrc2 + zero pad rows
    prep_kernel<<<512, 256, 0, stream>>>(X, W1, W2, W3, Xb, bufY, bufH,
                                         W1b, W2b, W3b, cur2, esrc2);
    // 2: (dst, src>>10) sub-bin place
    place_kernel<<<(N_EDGES + 255) / 256, 256, 0, stream>>>(edges, cur2, esrc2);
    // 3: gather layer-1 (src-phased, L2-local)
    gather_kernel<<<N_NODES / 4, 256, 0, stream>>>(Xb, cur2, esrc2, Ag1, degF);
    // 4: layer-1 transform: bufY = relu(Ag1@W1 + deg*b1)
    gemm_kernel<false><<<157, 512, 0, stream>>>(Ag1, W1b, b1, degF, W3b, b3, bufY);
    // 5: gather layer-2
    gather_kernel<<<N_NODES / 4, 256, 0, stream>>>(bufY, cur2, esrc2, Ag2, degF);
    // 6: layer-2 transform + chained layer-3 -> bufH
    gemm_kernel<true><<<157, 512, 0, stream>>>(Ag2, W2b, b2, degF, W3b, b3, bufH);
    // 7: final aggregation + relu -> d_out (f32)
    agg_relu_40_kernel<<<N_NODES / 4, 256, 0, stream>>>(bufH, cur2, esrc2, out);
}

// Round 6
// 159.206 us; speedup vs baseline: 1.0670x; 1.0670x over previous
//
#include <hip/hip_runtime.h>

// NodeClassifier 3-layer MP-GNN, MI355X. R11: warm-sweep the gather arrays.
// Budget (from R8 profile arithmetic): layers ~28us each in R7; prep+place+
// agg40+gaps ~103us?! and R2's layer FETCH_SIZE=36.5MB vs ~10MB compulsory:
// the inter-iteration 268MB ws poison flushes L3, so the random gather
// demand-misses to HBM (~900cy) line-by-line. Fix: leading linear warm-sweep
// (one coalesced grid pass, ~1us) streams the 5MB feature array into L2/L3
// before the random phase. Also: revert R10's sub-bin gather (2-load batches
// serialized on latency; R9's 8-load batches restored), drop esrc dummy-fill
// (clamp to DUMMY per slot instead), keep R10's W-resident zero-barrier gemm.
// Lessons: grid.sync ~35us (R3); fused gather+gemm idle pipes (R2); compiler
// defeats source-level load pipelines (R8); short-batch bins serialize (R10).

#define N_NODES   10000
#define N_EDGES   320000
#define D_HID     256
#define N_CLASSES 40
#define CAP       96
#define DUMMY     10000  // padding node; its rows are zeroed in prep

typedef __attribute__((ext_vector_type(8))) short short8;
typedef __attribute__((ext_vector_type(4))) float f32x4;

__device__ __forceinline__ ushort f2bf(float f) {
    unsigned u = __float_as_uint(f);
    u = (u + 0x7fffu + ((u >> 16) & 1u)) >> 16;   // RNE; inputs finite
    return (ushort)u;
}
__device__ __forceinline__ float bf2f(ushort u) {
    return __uint_as_float(((unsigned)u) << 16);
}

// ---------------- prep: zero cursor, pad rows, bf16 conversions ----------------

__global__ __launch_bounds__(256)
void prep_kernel(const float* __restrict__ X,
                 const float* __restrict__ W1, const float* __restrict__ W2,
                 const float* __restrict__ W3,
                 ushort* __restrict__ Xb, ushort* __restrict__ bufY,
                 ushort* __restrict__ bufH,
                 ushort* __restrict__ W1b, ushort* __restrict__ W2b,
                 ushort* __restrict__ W3b, int* __restrict__ cursor) {
    const int tid  = blockIdx.x * 256 + threadIdx.x;
    const int nthr = gridDim.x * 256;
    for (int i = tid; i < N_NODES; i += nthr) cursor[i] = 0;
    // zero the padding rows (read by clamp-gather / agg40)
    ushort4 z; z.x = 0; z.y = 0; z.z = 0; z.w = 0;
    if (tid < 64) {
        ((ushort4*)Xb)[640000 + tid]   = z;   // row 10000 of Xb
        ((ushort4*)bufY)[640000 + tid] = z;   // row 10000 of bufY
    }
    if (tid < 10) ((ushort4*)bufH)[100000 + tid] = z;  // row 10000 of bufH
    // X -> bf16
    for (int i = tid; i < N_NODES * D_HID / 4; i += nthr) {
        float4 v = ((const float4*)X)[i];
        ushort4 o;
        o.x = f2bf(v.x); o.y = f2bf(v.y); o.z = f2bf(v.z); o.w = f2bf(v.w);
        ((ushort4*)Xb)[i] = o;
    }
    // weights -> bf16, transposed to n-major
    for (int i = tid; i < 141312; i += nthr) {
        if (i < 65536) {
            int n = i >> 8, k = i & 255;
            W1b[i] = f2bf(W1[k * 256 + n]);
        } else if (i < 131072) {
            int t2 = i - 65536;
            int n = t2 >> 8, k = t2 & 255;
            W2b[t2] = f2bf(W2[k * 256 + n]);
        } else {
            int t2 = i - 131072;
            int n = t2 >> 8, k = t2 & 255;
            W3b[t2] = f2bf(W3[k * N_CLASSES + n]);
        }
    }
}

// ---------------- place: bucket CSR via global atomics ----------------

__global__ __launch_bounds__(256)
void place_kernel(const int* __restrict__ edges, int* __restrict__ cursor,
                  int* __restrict__ esrc) {
    int e = blockIdx.x * 256 + threadIdx.x;
    if (e < N_EDGES) {
        int d = edges[N_EDGES + e];
        int pos = atomicAdd(&cursor[d], 1);
        if (pos < CAP) esrc[d * CAP + pos] = edges[e];
    }
}

// ---------------- gather: warm-sweep + Ag[n] = sum_edges Xin[src] ----------------
// 1 wave = 1 node, 4/block, 2500 blocks. Leading warm-sweep: the whole grid
// streams Xin (5MB) once, coalesced, pulling it HBM->L2/L3 before the random
// phase (poison between iterations leaves it cold; R2 showed 36.5MB HBM
// FETCH/layer = line-by-line demand misses). Batch = 16 edges = 8 uint4 loads
// (lanes 0-31 edge 2u, 32-63 edge 2u+1); slots >= cnt clamp to DUMMY (zero
// row). Halves combined via shfl_xor(32).

__global__ __launch_bounds__(256)
void gather_kernel(const ushort* __restrict__ Xin, const int* __restrict__ deg,
                   const int* __restrict__ esrc, ushort* __restrict__ Ag,
                   float* __restrict__ degOut) {
    __shared__ int eidx[4 * CAP];     // 1536 B
    __shared__ int degL[4];

    const int tid  = threadIdx.x;
    const int w    = tid >> 6, lane = tid & 63;
    const int lo   = lane & 31, hi = lane >> 5;
    const int base = blockIdx.x * 4;
    const uint4* hp4 = (const uint4*)Xin;

    // warm-sweep: one coalesced pass over rows 0..9999 (320000 uint4 total)
    {
        int i = blockIdx.x * 256 + tid;
        if (i < 320000) {
            uint4 t = hp4[i];
            asm volatile("" :: "v"(t.x), "v"(t.y), "v"(t.z), "v"(t.w));
        }
    }

    for (int i = tid; i < 4 * CAP; i += 256)
        eidx[i] = esrc[base * CAP + i];     // slots >= cnt are poison (never used)
    if (tid < 4) degL[tid] = deg[base + tid];
    __syncthreads();

    const int node = base + w;
    const int raw  = degL[w];
    const int cnt  = raw < CAP ? raw : CAP;
    const int nb   = (cnt + 15) >> 4;       // batches of 16 edges

    float a[8] = {};
    for (int b = 0; b < nb; ++b) {
        uint4 v[8];
#pragma unroll
        for (int u = 0; u < 8; ++u) {
            int slot = b * 16 + 2 * u + hi;
            int e = (slot < cnt) ? eidx[w * CAP + slot] : DUMMY;  // zero row
            v[u] = hp4[(size_t)e * 32 + lo];                      // 16B/lane
        }
#pragma unroll
        for (int u = 0; u < 8; ++u) {
            a[0] += bf2f((ushort)(v[u].x & 0xffff)); a[1] += bf2f((ushort)(v[u].x >> 16));
            a[2] += bf2f((ushort)(v[u].y & 0xffff)); a[3] += bf2f((ushort)(v[u].y >> 16));
            a[4] += bf2f((ushort)(v[u].z & 0xffff)); a[5] += bf2f((ushort)(v[u].z >> 16));
            a[6] += bf2f((ushort)(v[u].w & 0xffff)); a[7] += bf2f((ushort)(v[u].w >> 16));
        }
    }
#pragma unroll
    for (int j = 0; j < 8; ++j) a[j] += __shfl_xor(a[j], 32);
    if (lane < 32) {
        uint4 o;
        o.x = (unsigned)f2bf(a[0]) | ((unsigned)f2bf(a[1]) << 16);
        o.y = (unsigned)f2bf(a[2]) | ((unsigned)f2bf(a[3]) << 16);
        o.z = (unsigned)f2bf(a[4]) | ((unsigned)f2bf(a[5]) << 16);
        o.w = (unsigned)f2bf(a[6]) | ((unsigned)f2bf(a[7]) << 16);
        ((uint4*)(Ag + (size_t)node * 256))[lo] = o;   // zero-deg -> zero row
    }
    if (lane == 0) degOut[node] = (float)raw;          // true degree (bias term)
}

// ---------------- gemm: Out = relu(Ag @ W + deg*b)  [+ chained @W3 + b3] ----------------
// 64 rows x 256 cols per block, 512 threads (8 waves: 4 rowGrp x 2 colGrp),
// 157 blocks (157*64 = 10048). W staged to LDS ONCE (256x264 stride), A-frags
// preloaded to regs from global, k-loop = 64 MFMA back-to-back, ZERO barriers
// inside. Rows 10000..10047 are pad: poison stays in its own C row; stores
// guarded. (Ran correct inside R10b.)

#define LDSB 264

template<bool CHAIN>
__global__ __launch_bounds__(512)
void gemm_kernel(const ushort* __restrict__ Ag, const ushort* __restrict__ Bt,
                 const float* __restrict__ bias, const float* __restrict__ degF,
                 const ushort* __restrict__ W3b, const float* __restrict__ b3,
                 ushort* __restrict__ Out) {
    __shared__ ushort Bs[256 * LDSB];     // 135,168 B; W-main, reused as out2 when CHAIN
    __shared__ ushort W3L[40 * LDSB];     // 21,120 B (staged only when CHAIN)
    __shared__ float  degL[64];

    const int tid  = threadIdx.x;
    const int wave = tid >> 6, lane = tid & 63;
    const int lr = lane & 15, lg = lane >> 4;
    const int rg = wave >> 1, cg = wave & 1;
    const int rowBase = blockIdx.x * 64;

    // stage W: 256 n-rows x 256 k -> Bs[n*LDSB + k]; 8192 16B chunks
#pragma unroll
    for (int p = 0; p < 16; ++p) {
        int idx = p * 512 + tid;
        int n = idx >> 5, c = (idx & 31) * 8;
        *(uint4*)(Bs + n * LDSB + c) = *(const uint4*)(Bt + (size_t)n * 256 + c);
    }
    if (CHAIN) {
#pragma unroll
        for (int p = 0; p < 3; ++p) {
            int idx = p * 512 + tid;
            if (idx < 1280) {
                int n = idx >> 5, c = (idx & 31) * 8;
                *(uint4*)(W3L + n * LDSB + c) = *(const uint4*)(W3b + (size_t)n * 256 + c);
            }
        }
    }
    if (tid < 64) degL[tid] = degF[rowBase + tid];

    // preload all 8 A-fragments (this wave's 16 rows, full K) from global
    short8 afr[8];
    const size_t aBase = (size_t)(rowBase + rg * 16 + lr) * 256 + lg * 8;
#pragma unroll
    for (int ks = 0; ks < 8; ++ks)
        afr[ks] = *(const short8*)(Ag + aBase + ks * 32);

    __syncthreads();

    f32x4 acc[8] = {};
#pragma unroll
    for (int ks = 0; ks < 8; ++ks) {
        int k0 = ks * 32;
#pragma unroll
        for (int j = 0; j < 8; ++j) {
            short8 bf = *(const short8*)(Bs + (cg * 128 + j * 16 + lr) * LDSB + k0 + lg * 8);
            acc[j] = __builtin_amdgcn_mfma_f32_16x16x32_bf16(afr[ks], bf, acc[j], 0, 0, 0);
        }
    }

    if (!CHAIN) {
#pragma unroll
        for (int j = 0; j < 8; ++j) {
            int col = cg * 128 + j * 16 + lr;
            float bv = bias[col];
#pragma unroll
            for (int r = 0; r < 4; ++r) {
                int rl = rg * 16 + lg * 4 + r;
                int grow = rowBase + rl;
                if (grow < N_NODES)
                    Out[(size_t)grow * 256 + col] =
                        f2bf(fmaxf(fmaf(degL[rl], bv, acc[j][r]), 0.f));
            }
        }
    } else {
        __syncthreads();   // all Bs reads done before overwrite
        // out2 = relu(acc + deg*b) -> Bs area as As3[64][LDSB] (bf16)
#pragma unroll
        for (int j = 0; j < 8; ++j) {
            int col = cg * 128 + j * 16 + lr;
            float bv = bias[col];
#pragma unroll
            for (int r = 0; r < 4; ++r) {
                int rl = rg * 16 + lg * 4 + r;
                Bs[rl * LDSB + col] = f2bf(fmaxf(fmaf(degL[rl], bv, acc[j][r]), 0.f));
            }
        }
        __syncthreads();
        // gemm3: h3 = out2 @ W3 + b3. 12 tiles (4 rowT x 3 colT, mask 40).
        for (int t = wave; t < 12; t += 8) {
            int rT = t & 3, cT = t >> 2;
            f32x4 a3 = {};
#pragma unroll
            for (int ks = 0; ks < 8; ++ks) {
                short8 af = *(const short8*)(Bs + (rT * 16 + lr) * LDSB + ks * 32 + lg * 8);
                short8 bf = *(const short8*)(W3L + (cT * 16 + lr) * LDSB + ks * 32 + lg * 8);
                a3 = __builtin_amdgcn_mfma_f32_16x16x32_bf16(af, bf, a3, 0, 0, 0);
            }
            int col = cT * 16 + lr;
            if (col < N_CLASSES) {
                float bv = b3[col];
#pragma unroll
                for (int r = 0; r < 4; ++r) {
                    int grow = rowBase + rT * 16 + lg * 4 + r;
                    if (grow < N_NODES)
                        Out[(size_t)grow * N_CLASSES + col] = f2bf(a3[r] + bv);
                }
            }
        }
    }
}

// ---------------- agg40: out = relu(segsum(h3[src])) -> f32 ----------------
// One wave per node. 6 edges per load instr (10 lanes x 4 cols each, lanes
// 60-63 duplicate lane 0); slots >= cnt clamp to DUMMY (zero row); 3-round
// shuffle fold; float4 stores.

__global__ __launch_bounds__(256)
void agg_relu_40_kernel(const ushort* __restrict__ h, const int* __restrict__ deg,
                        const int* __restrict__ esrc, float* __restrict__ out) {
    const int wv   = threadIdx.x >> 6;
    const int lane = threadIdx.x & 63;
    const int node = (blockIdx.x << 2) + wv;
    const int l6   = (lane < 60) ? lane : 0;
    const int g6   = l6 / 10;                 // edge-in-batch 0..5
    const int c10  = l6 - g6 * 10;            // col group 0..9 (cols 4*c10..+3)

    int cnt = deg[node];
    if (cnt > CAP) cnt = CAP;
    const int* ep = esrc + node * CAP;
    float a0 = 0.f, a1 = 0.f, a2 = 0.f, a3 = 0.f;
    for (int b = 0; b < cnt; b += 6) {
        int slot = b + g6;
        int s = (slot < cnt) ? ep[slot] : DUMMY;   // zero row for pad lanes
        uint2 v = *(const uint2*)(h + (size_t)s * N_CLASSES + c10 * 4);
        a0 += bf2f((ushort)(v.x & 0xffff)); a1 += bf2f((ushort)(v.x >> 16));
        a2 += bf2f((ushort)(v.y & 0xffff)); a3 += bf2f((ushort)(v.y >> 16));
    }
    // fold 6 edge-groups down to group 0 (lanes 0..9): +30, then +10 and +20
#define FOLD40(x) { x += __shfl(x, lane + 30);                      \
                    float t1 = __shfl(x, lane + 10);                \
                    float t2 = __shfl(x, lane + 20);                \
                    x += t1 + t2; }
    FOLD40(a0); FOLD40(a1); FOLD40(a2); FOLD40(a3);
#undef FOLD40
    if (lane < 10) {
        float4 o;
        o.x = fmaxf(a0, 0.f); o.y = fmaxf(a1, 0.f);
        o.z = fmaxf(a2, 0.f); o.w = fmaxf(a3, 0.f);
        *(float4*)(out + (size_t)node * N_CLASSES + lane * 4) = o;
    }
}

// ---------------- launch ----------------

extern "C" void kernel_launch(void* const* d_in, const int* in_sizes, int n_in,
                              void* d_out, int out_size, void* d_ws, size_t ws_size,
                              hipStream_t stream) {
    const float* X     = (const float*)d_in[0];
    const int*   edges = (const int*)d_in[1];
    const float* W1 = (const float*)d_in[2];
    const float* b1 = (const float*)d_in[3];
    const float* W2 = (const float*)d_in[4];
    const float* b2 = (const float*)d_in[5];
    const float* W3 = (const float*)d_in[6];
    const float* b3 = (const float*)d_in[7];
    float* out = (float*)d_out;

    char* ws = (char*)d_ws;
    ushort* Xb    = (ushort*)(ws);                   //  5,120,512 B (10001 x 256)
    ushort* bufY  = (ushort*)(ws + 5120512);         //  5,120,512 B (10001 x 256)
    ushort* bufH  = (ushort*)(ws + 10241024);        //    800,080 B (10001 x 40)
    ushort* W1b   = (ushort*)(ws + 11041104);        //    131,072 B (n-major)
    ushort* W2b   = (ushort*)(ws + 11172176);        //    131,072 B
    ushort* W3b   = (ushort*)(ws + 11303248);        //     20,480 B
    int*    cursor= (int*)(ws + 11323728);           //     40,000 B (== deg after place)
    int*    esrc  = (int*)(ws + 11363728);           //  3,840,000 B (10000 x 96)
    ushort* Ag1   = (ushort*)(ws + 15203728);        //  5,144,576 B (10048 x 256)
    ushort* Ag2   = (ushort*)(ws + 20348304);        //  5,144,576 B
    float*  degF  = (float*)(ws + 25492880);         //     40,192 B (10048)

    // 1: conversions + zero cursor + zero pad rows (no esrc fill: clamp instead)
    prep_kernel<<<512, 256, 0, stream>>>(X, W1, W2, W3, Xb, bufY, bufH,
                                         W1b, W2b, W3b, cursor);
    // 2: bucket-CSR place
    place_kernel<<<(N_EDGES + 255) / 256, 256, 0, stream>>>(edges, cursor, esrc);
    // 3: gather layer-1 (warm-sweep + high TLP)
    gather_kernel<<<N_NODES / 4, 256, 0, stream>>>(Xb, cursor, esrc, Ag1, degF);
    // 4: layer-1 transform: bufY = relu(Ag1@W1 + deg*b1)
    gemm_kernel<false><<<157, 512, 0, stream>>>(Ag1, W1b, b1, degF, W3b, b3, bufY);
    // 5: gather layer-2
    gather_kernel<<<N_NODES / 4, 256, 0, stream>>>(bufY, cursor, esrc, Ag2, degF);
    // 6: layer-2 transform + chained layer-3 -> bufH
    gemm_kernel<true><<<157, 512, 0, stream>>>(Ag2, W2b, b2, degF, W3b, b3, bufH);
    // 7: final aggregation + relu -> d_out (f32)
    agg_relu_40_kernel<<<N_NODES / 4, 256, 0, stream>>>(bufH, cursor, esrc, out);
}